// Round 8
// baseline (196.858 us; speedup 1.0000x reference)
//
#include <hip/hip_runtime.h>
#include <hip/hip_bf16.h>

#define LL 2048
#define DM 512
#define SCALE 0.02209708691207961f   // 1/sqrt(2048)

typedef unsigned short u16;
typedef __attribute__((ext_vector_type(8))) short short8;    // 8 bf16 (4 VGPRs)
typedef __attribute__((ext_vector_type(4))) short short4v;   // 4 bf16 (2 VGPRs)
typedef __attribute__((ext_vector_type(4))) float f32x4;     // MFMA C/D

// ws layout (u16 element offsets), ~58 MB of the 256 MiB ws:
//  XAQ/XAK/XAV: bf16 inputs in proj-A-frag order [2][128 r16][16 kt][64 lane][8]
//  WB : bf16 weights in B-frag order [3][8][16 kt][4 nt][64 lane][8]
//  QA/KA: bf16 Q,K projections in frag order (Q pre-scaled by SCALE)
//  VB : bf16 V in PV-B-frag order (RAW — Sinv now applied in attn via rcp(S))
//  S  : f32 column sums [16][2048] (atomic-accumulated; prep zeroes)
//  PART: f32 attn partials [4 ks][16 bh][32 QT][64 row][64 e]
#define XAQ_OFF 0u
#define XAK_OFF 2097152u
#define XAV_OFF 4194304u
#define WB_OFF  6291456u
#define QA_OFF  7077888u
#define KA_OFF  9175040u
#define VB_OFF  11272192u
#define S_OFF   13369344u    // float* region, 32768 floats
#define PART_OFF 13434880u   // float* region, 8,388,608 floats (32 MB)

__device__ __forceinline__ u16 f2bf(float f) {
  union { float f; unsigned u; } v; v.f = f;
  unsigned r = v.u + 0x7fff + ((v.u >> 16) & 1);   // RNE
  return (u16)(r >> 16);
}
__device__ __forceinline__ size_t frag_idx(int bh, int t64, int w, int c, int lane) {
  return ((((size_t)(bh * 32 + t64) * 4 + w) * 2 + c) * 64 + lane) * 8;
}
__device__ __forceinline__ size_t vb_idx(int bh, int kt, int w, int et, int lane) {
  return ((((size_t)(bh * 32 + kt) * 4 + w) * 4 + et) * 64 + lane) * 4;
}

// ---------------- prep: X -> frag order via LDS transpose; W -> B-frag order; zero S ----------------
__global__ __launch_bounds__(256) void prep_kernel(
    const float* __restrict__ queries, const float* __restrict__ keys,
    const float* __restrict__ values, const float* __restrict__ WQ,
    const float* __restrict__ WK, const float* __restrict__ WV,
    u16* __restrict__ wsb) {
  int t = threadIdx.x;
  int blk = blockIdx.x;
  if (blk < 768) {
    int tens = blk >> 8;                       // 0=Q,1=K,2=V
    int grp  = blk & 255;                      // b*128 + r16
    const float* src = (tens == 0 ? queries : tens == 1 ? keys : values) +
                       (size_t)grp * 16 * 512;
    __shared__ __align__(16) u16 Xs[16][520];
#pragma unroll
    for (int rep = 0; rep < 8; ++rep) {
      int f4 = t + rep * 256;                  // 0..2047
      int row = f4 >> 7, c4 = f4 & 127;
      float4 v = *(const float4*)(src + (size_t)row * 512 + c4 * 4);
      short4v o;
      o[0] = (short)f2bf(v.x); o[1] = (short)f2bf(v.y);
      o[2] = (short)f2bf(v.z); o[3] = (short)f2bf(v.w);
      *(short4v*)&Xs[row][c4 * 4] = o;
    }
    __syncthreads();
    u16* dst = wsb + (tens == 0 ? XAQ_OFF : tens == 1 ? XAK_OFF : XAV_OFF) +
               (size_t)grp * 16 * 64 * 8;
#pragma unroll
    for (int rep = 0; rep < 4; ++rep) {
      int o = t + rep * 256;                   // kt*64 + lane
      int kt = o >> 6, lane = o & 63;
      int quad = lane >> 4, l16 = lane & 15;
      short8 v = *(const short8*)&Xs[l16][kt * 32 + quad * 8];
      *(short8*)(dst + (size_t)o * 8) = v;
    }
  } else if (blk < 1152) {
    int c2 = (blk - 768) * 256 + t;            // 0..98303
    int lane = c2 & 63;
    int nt = (c2 >> 6) & 3;
    int kt = (c2 >> 8) & 15;
    int h  = (c2 >> 12) & 7;
    int z  = c2 >> 15;
    int quad = lane >> 4, l16 = lane & 15;
    const float* W = (z == 0) ? WQ : (z == 1) ? WK : WV;
    const float* src = W + ((size_t)h * DM + kt * 32 + quad * 8) * 64 + nt * 16 + l16;
    short8 o;
#pragma unroll
    for (int j = 0; j < 8; ++j) o[j] = (short)f2bf(src[(size_t)j * 64]);
    *(short8*)(wsb + WB_OFF + (size_t)c2 * 8) = o;
  } else {
    // zero S: 32 blocks x 256 threads x 1 float4 = 8192 float4s
    float* S = (float*)(wsb + S_OFF);
    int idx = (blk - 1152) * 256 + t;
    ((float4*)S)[idx] = (float4){0.f, 0.f, 0.f, 0.f};
  }
}

// ---------------- proj: barrier-free MFMA GEMM; coalesced frag-order epilogue via LDS ----------------
__global__ __launch_bounds__(256) void proj_kernel(u16* __restrict__ wsb) {
  int t = threadIdx.x;
  int lane = t & 63, w = t >> 6, quad = lane >> 4, l16 = lane & 15;
  int z = blockIdx.z, bh = blockIdx.y, b = bh >> 3, h = bh & 7;
  int QT = blockIdx.x;

  const u16* Bw = wsb + WB_OFF + ((size_t)(z * 8 + h) * 16) * 4 * 64 * 8;
  const u16* Ab = wsb + (z == 0 ? XAQ_OFF : z == 1 ? XAK_OFF : XAV_OFF) +
      (((size_t)b * 128 + QT * 4 + w) * 16) * 64 * 8;

  f32x4 acc[4];
#pragma unroll
  for (int nt = 0; nt < 4; ++nt) acc[nt] = (f32x4){0.f, 0.f, 0.f, 0.f};

#pragma unroll 4
  for (int kt = 0; kt < 16; ++kt) {
    short8 a = *(const short8*)(Ab + ((size_t)kt * 64 + lane) * 8);
#pragma unroll
    for (int nt = 0; nt < 4; ++nt) {
      short8 bb = *(const short8*)(Bw + (((size_t)kt * 4 + nt) * 64 + lane) * 8);
      acc[nt] = __builtin_amdgcn_mfma_f32_16x16x32_bf16(a, bb, acc[nt], 0, 0, 0);
    }
  }

  __shared__ float Cs[64][68];
  float sc = (z == 0) ? SCALE : 1.0f;
#pragma unroll
  for (int nt = 0; nt < 4; ++nt)
#pragma unroll
    for (int r = 0; r < 4; ++r)
      Cs[w * 16 + quad * 4 + r][nt * 16 + l16] = acc[nt][r] * sc;
  __syncthreads();

  if (z < 2) {
    u16* base = wsb + (z == 0 ? QA_OFF : KA_OFF);
#pragma unroll
    for (int c = 0; c < 2; ++c) {
      const float* srcr = &Cs[w * 16 + l16][c * 32 + quad * 8];
      short8 o;
#pragma unroll
      for (int j = 0; j < 8; ++j) o[j] = (short)f2bf(srcr[j]);
      *(short8*)(base + frag_idx(bh, QT, w, c, lane)) = o;
    }
  } else {
#pragma unroll
    for (int et = 0; et < 4; ++et) {
      short4v o;
#pragma unroll
      for (int j = 0; j < 4; ++j)
        o[j] = (short)f2bf(Cs[w * 16 + quad * 4 + j][et * 16 + l16]);
      *(short4v*)(wsb + VB_OFF + vb_idx(bh, QT, w, et, lane)) = o;
    }
  }
}

// ---------------- stats: q-split column sums, atomicAdd into S ----------------
__global__ __launch_bounds__(256, 4) void stats_kernel(u16* __restrict__ wsb) {
  int t = threadIdx.x;
  int lane = t & 63, w = t >> 6, quad = lane >> 4, l16 = lane & 15;
  int bh = blockIdx.y;
  int KT = blockIdx.x;
  int qs = blockIdx.z;

  short8 ka[4][2];
#pragma unroll
  for (int mt = 0; mt < 4; ++mt)
#pragma unroll
    for (int c = 0; c < 2; ++c)
      ka[mt][c] = *(const short8*)(wsb + KA_OFF + frag_idx(bh, KT, mt, c, lane));

  float rs[4][4];
#pragma unroll
  for (int mt = 0; mt < 4; ++mt)
#pragma unroll
    for (int r = 0; r < 4; ++r) rs[mt][r] = 0.f;

  for (int qt = qs * 8; qt < qs * 8 + 8; ++qt) {
    short8 qb0 = *(const short8*)(wsb + QA_OFF + frag_idx(bh, qt, w, 0, lane));
    short8 qb1 = *(const short8*)(wsb + QA_OFF + frag_idx(bh, qt, w, 1, lane));
#pragma unroll
    for (int mt = 0; mt < 4; ++mt) {
      f32x4 y = (f32x4){0.f, 0.f, 0.f, 0.f};
      y = __builtin_amdgcn_mfma_f32_16x16x32_bf16(ka[mt][0], qb0, y, 0, 0, 0);
      y = __builtin_amdgcn_mfma_f32_16x16x32_bf16(ka[mt][1], qb1, y, 0, 0, 0);
#pragma unroll
      for (int r = 0; r < 4; ++r) rs[mt][r] += __expf(y[r]);
    }
  }
#pragma unroll
  for (int mt = 0; mt < 4; ++mt)
#pragma unroll
    for (int r = 0; r < 4; ++r) {
      rs[mt][r] += __shfl_xor(rs[mt][r], 1);
      rs[mt][r] += __shfl_xor(rs[mt][r], 2);
      rs[mt][r] += __shfl_xor(rs[mt][r], 4);
      rs[mt][r] += __shfl_xor(rs[mt][r], 8);
    }

  __shared__ float Sred[4][64];
  if (l16 == 0) {
#pragma unroll
    for (int mt = 0; mt < 4; ++mt)
#pragma unroll
      for (int r = 0; r < 4; ++r)
        Sred[w][mt * 16 + quad * 4 + r] = rs[mt][r];
  }
  __syncthreads();
  if (t < 64) {
    float s = Sred[0][t] + Sred[1][t] + Sred[2][t] + Sred[3][t];
    float* S = (float*)(wsb + S_OFF);
    atomicAdd(&S[(size_t)bh * LL + KT * 64 + t], s);
  }
}

// ---------------- attn: k-split; P = exp(y)*rcp(S[k]) in registers; partials to ws ----------------
__global__ __launch_bounds__(256, 3) void attn_kernel(const u16* __restrict__ wsb,
                                                      float* __restrict__ part) {
  int t = threadIdx.x;
  int lane = t & 63, w = t >> 6, quad = lane >> 4, l16 = lane & 15;
  int bh = blockIdx.y;
  int QT = blockIdx.x;
  int ks = blockIdx.z;
  const float* S = (const float*)(wsb + S_OFF) + (size_t)bh * LL;

  short8 qf[4][2];
#pragma unroll
  for (int nt = 0; nt < 4; ++nt)
#pragma unroll
    for (int c = 0; c < 2; ++c)
      qf[nt][c] = *(const short8*)(wsb + QA_OFF + frag_idx(bh, QT, nt, c, lane));

  f32x4 oacc[4][4];
#pragma unroll
  for (int nt = 0; nt < 4; ++nt)
#pragma unroll
    for (int et = 0; et < 4; ++et) oacc[nt][et] = (f32x4){0.f, 0.f, 0.f, 0.f};

  for (int kt = ks * 8; kt < ks * 8 + 8; ++kt) {
    short8 ka0 = *(const short8*)(wsb + KA_OFF + frag_idx(bh, kt, w, 0, lane));
    short8 ka1 = *(const short8*)(wsb + KA_OFF + frag_idx(bh, kt, w, 1, lane));
    short4v vb[4];
#pragma unroll
    for (int et = 0; et < 4; ++et)
      vb[et] = *(const short4v*)(wsb + VB_OFF + vb_idx(bh, kt, w, et, lane));
    // Sinv for this lane's 4 k values (broadcast float4 within each quad)
    float4 s4 = *(const float4*)(S + kt * 64 + w * 16 + quad * 4);
    float si[4];
    si[0] = __builtin_amdgcn_rcpf(s4.x);
    si[1] = __builtin_amdgcn_rcpf(s4.y);
    si[2] = __builtin_amdgcn_rcpf(s4.z);
    si[3] = __builtin_amdgcn_rcpf(s4.w);

#pragma unroll
    for (int nt = 0; nt < 4; ++nt) {
      f32x4 y = (f32x4){0.f, 0.f, 0.f, 0.f};
      y = __builtin_amdgcn_mfma_f32_16x16x32_bf16(ka0, qf[nt][0], y, 0, 0, 0);
      y = __builtin_amdgcn_mfma_f32_16x16x32_bf16(ka1, qf[nt][1], y, 0, 0, 0);
      short4v pa;
#pragma unroll
      for (int r = 0; r < 4; ++r) pa[r] = (short)f2bf(__expf(y[r]) * si[r]);
#pragma unroll
      for (int et = 0; et < 4; ++et)
        oacc[nt][et] = __builtin_amdgcn_mfma_f32_16x16x16bf16_1k(pa, vb[et], oacc[nt][et], 0, 0, 0);
    }
  }

  // 2-stage cross-wave k-reduction in 34.8 KB LDS (4 blocks/CU legal)
  __shared__ float red[2][64][68];
  if (w >= 2) {
#pragma unroll
    for (int nt = 0; nt < 4; ++nt)
#pragma unroll
      for (int et = 0; et < 4; ++et)
#pragma unroll
        for (int r = 0; r < 4; ++r)
          red[w - 2][nt * 16 + quad * 4 + r][et * 16 + l16] = oacc[nt][et][r];
  }
  __syncthreads();
  if (w < 2) {
#pragma unroll
    for (int nt = 0; nt < 4; ++nt)
#pragma unroll
      for (int et = 0; et < 4; ++et)
#pragma unroll
        for (int r = 0; r < 4; ++r) {
          float v = oacc[nt][et][r] + red[w][nt * 16 + quad * 4 + r][et * 16 + l16];
          red[w][nt * 16 + quad * 4 + r][et * 16 + l16] = v;
        }
  }
  __syncthreads();
  float* pg = part + (((size_t)(ks * 16 + bh) * 32 + QT) * 64) * 64;
#pragma unroll
  for (int i = 0; i < 16; ++i) {
    float s = red[0][w * 16 + i][lane] + red[1][w * 16 + i][lane];
    pg[(size_t)(w * 16 + i) * 64 + lane] = s;
  }
}

// ---------------- reduce: out = sum_ks part ----------------
__global__ __launch_bounds__(256) void reduce_kernel(const float* __restrict__ part,
                                                     float* __restrict__ out) {
  int g = blockIdx.x * 256 + threadIdx.x;      // 0..524287
  int e4 = g & 15;
  int row = (g >> 4) & 63;
  int QT = (g >> 10) & 31;
  int bh = g >> 15;
  size_t pidx = (((size_t)bh * 32 + QT) * 64 + row) * 64 + e4 * 4;
  float4 a = *(const float4*)(part + pidx);
  float4 b = *(const float4*)(part + pidx + 2097152);
  float4 c = *(const float4*)(part + pidx + 2 * 2097152);
  float4 d = *(const float4*)(part + pidx + 3 * 2097152);
  float4 o;
  o.x = a.x + b.x + c.x + d.x;
  o.y = a.y + b.y + c.y + d.y;
  o.z = a.z + b.z + c.z + d.z;
  o.w = a.w + b.w + c.w + d.w;
  int b_ = bh >> 3, h = bh & 7;
  *(float4*)(out + ((size_t)(b_ * 2048 + QT * 64 + row) * 512) + h * 64 + e4 * 4) = o;
}

extern "C" void kernel_launch(void* const* d_in, const int* in_sizes, int n_in,
                              void* d_out, int out_size, void* d_ws, size_t ws_size,
                              hipStream_t stream) {
  const float* keys    = (const float*)d_in[0];
  const float* queries = (const float*)d_in[1];
  const float* values  = (const float*)d_in[2];
  const float* WQ      = (const float*)d_in[3];
  const float* WK      = (const float*)d_in[4];
  const float* WV      = (const float*)d_in[5];
  float* out = (float*)d_out;
  u16* wsb = (u16*)d_ws;
  float* part = (float*)(wsb + PART_OFF);

  prep_kernel<<<dim3(1184), 256, 0, stream>>>(queries, keys, values, WQ, WK, WV, wsb);
  proj_kernel<<<dim3(32, 16, 3), 256, 0, stream>>>(wsb);
  stats_kernel<<<dim3(32, 16, 4), 256, 0, stream>>>(wsb);
  attn_kernel<<<dim3(32, 16, 4), 256, 0, stream>>>(wsb, part);
  reduce_kernel<<<dim3(2048), 256, 0, stream>>>(part, out);
}

// Round 9
// 139.959 us; speedup vs baseline: 1.4065x; 1.4065x over previous
//
#include <hip/hip_runtime.h>
#include <hip/hip_bf16.h>

#define LL 2048
#define DM 512
#define SCALE 0.02209708691207961f   // 1/sqrt(2048)

typedef unsigned short u16;
typedef __attribute__((ext_vector_type(8))) short short8;    // 8 bf16 (4 VGPRs)
typedef __attribute__((ext_vector_type(4))) short short4v;   // 4 bf16 (2 VGPRs)
typedef __attribute__((ext_vector_type(4))) float f32x4;     // MFMA C/D

// ws layout (u16 element offsets), ~27 MB of the 256 MiB ws:
//  XAQ/XAK/XAV: bf16 inputs in proj-A-frag order [2][128 r16][16 kt][64 lane][8]
//  WB : bf16 weights in B-frag order [3][8][16 kt][4 nt][64 lane][8]
//  QA/KA: bf16 Q,K projections in frag order (Q pre-scaled by SCALE)
//  VB : bf16 V in PV-B-frag order (RAW; Sinv applied to P in attn)
//  S  : f32 Sinv [16][2048] (written by stats, one block per (bh,KT))
#define XAQ_OFF 0u
#define XAK_OFF 2097152u
#define XAV_OFF 4194304u
#define WB_OFF  6291456u
#define QA_OFF  7077888u
#define KA_OFF  9175040u
#define VB_OFF  11272192u
#define S_OFF   13369344u    // float region, 32768 floats

__device__ __forceinline__ u16 f2bf(float f) {
  union { float f; unsigned u; } v; v.f = f;
  unsigned r = v.u + 0x7fff + ((v.u >> 16) & 1);   // RNE
  return (u16)(r >> 16);
}
__device__ __forceinline__ size_t frag_idx(int bh, int t64, int w, int c, int lane) {
  return ((((size_t)(bh * 32 + t64) * 4 + w) * 2 + c) * 64 + lane) * 8;
}
__device__ __forceinline__ size_t vb_idx(int bh, int kt, int w, int et, int lane) {
  return ((((size_t)(bh * 32 + kt) * 4 + w) * 4 + et) * 64 + lane) * 4;
}

// ---------------- prep: X -> frag order via LDS transpose; W -> B-frag order ----------------
__global__ __launch_bounds__(256) void prep_kernel(
    const float* __restrict__ queries, const float* __restrict__ keys,
    const float* __restrict__ values, const float* __restrict__ WQ,
    const float* __restrict__ WK, const float* __restrict__ WV,
    u16* __restrict__ wsb) {
  int t = threadIdx.x;
  int blk = blockIdx.x;
  if (blk < 768) {
    int tens = blk >> 8;                       // 0=Q,1=K,2=V
    int grp  = blk & 255;                      // b*128 + r16
    const float* src = (tens == 0 ? queries : tens == 1 ? keys : values) +
                       (size_t)grp * 16 * 512;
    __shared__ __align__(16) u16 Xs[16][520];
#pragma unroll
    for (int rep = 0; rep < 8; ++rep) {
      int f4 = t + rep * 256;                  // 0..2047
      int row = f4 >> 7, c4 = f4 & 127;
      float4 v = *(const float4*)(src + (size_t)row * 512 + c4 * 4);
      short4v o;
      o[0] = (short)f2bf(v.x); o[1] = (short)f2bf(v.y);
      o[2] = (short)f2bf(v.z); o[3] = (short)f2bf(v.w);
      *(short4v*)&Xs[row][c4 * 4] = o;
    }
    __syncthreads();
    u16* dst = wsb + (tens == 0 ? XAQ_OFF : tens == 1 ? XAK_OFF : XAV_OFF) +
               (size_t)grp * 16 * 64 * 8;
#pragma unroll
    for (int rep = 0; rep < 4; ++rep) {
      int o = t + rep * 256;                   // kt*64 + lane
      int kt = o >> 6, lane = o & 63;
      int quad = lane >> 4, l16 = lane & 15;
      short8 v = *(const short8*)&Xs[l16][kt * 32 + quad * 8];
      *(short8*)(dst + (size_t)o * 8) = v;
    }
  } else {
    int c2 = (blk - 768) * 256 + t;            // 0..98303
    int lane = c2 & 63;
    int nt = (c2 >> 6) & 3;
    int kt = (c2 >> 8) & 15;
    int h  = (c2 >> 12) & 7;
    int z  = c2 >> 15;
    int quad = lane >> 4, l16 = lane & 15;
    const float* W = (z == 0) ? WQ : (z == 1) ? WK : WV;
    const float* src = W + ((size_t)h * DM + kt * 32 + quad * 8) * 64 + nt * 16 + l16;
    short8 o;
#pragma unroll
    for (int j = 0; j < 8; ++j) o[j] = (short)f2bf(src[(size_t)j * 64]);
    *(short8*)(wsb + WB_OFF + (size_t)c2 * 8) = o;
  }
}

// ---------------- proj: barrier-free MFMA GEMM; coalesced frag-order epilogue via LDS ----------------
__global__ __launch_bounds__(256) void proj_kernel(u16* __restrict__ wsb) {
  int t = threadIdx.x;
  int lane = t & 63, w = t >> 6, quad = lane >> 4, l16 = lane & 15;
  int z = blockIdx.z, bh = blockIdx.y, b = bh >> 3, h = bh & 7;
  int QT = blockIdx.x;

  const u16* Bw = wsb + WB_OFF + ((size_t)(z * 8 + h) * 16) * 4 * 64 * 8;
  const u16* Ab = wsb + (z == 0 ? XAQ_OFF : z == 1 ? XAK_OFF : XAV_OFF) +
      (((size_t)b * 128 + QT * 4 + w) * 16) * 64 * 8;

  f32x4 acc[4];
#pragma unroll
  for (int nt = 0; nt < 4; ++nt) acc[nt] = (f32x4){0.f, 0.f, 0.f, 0.f};

#pragma unroll 4
  for (int kt = 0; kt < 16; ++kt) {
    short8 a = *(const short8*)(Ab + ((size_t)kt * 64 + lane) * 8);
#pragma unroll
    for (int nt = 0; nt < 4; ++nt) {
      short8 bb = *(const short8*)(Bw + (((size_t)kt * 4 + nt) * 64 + lane) * 8);
      acc[nt] = __builtin_amdgcn_mfma_f32_16x16x32_bf16(a, bb, acc[nt], 0, 0, 0);
    }
  }

  __shared__ float Cs[64][68];
  float sc = (z == 0) ? SCALE : 1.0f;
#pragma unroll
  for (int nt = 0; nt < 4; ++nt)
#pragma unroll
    for (int r = 0; r < 4; ++r)
      Cs[w * 16 + quad * 4 + r][nt * 16 + l16] = acc[nt][r] * sc;
  __syncthreads();

  if (z < 2) {
    u16* base = wsb + (z == 0 ? QA_OFF : KA_OFF);
#pragma unroll
    for (int c = 0; c < 2; ++c) {
      const float* srcr = &Cs[w * 16 + l16][c * 32 + quad * 8];
      short8 o;
#pragma unroll
      for (int j = 0; j < 8; ++j) o[j] = (short)f2bf(srcr[j]);
      *(short8*)(base + frag_idx(bh, QT, w, c, lane)) = o;
    }
  } else {
#pragma unroll
    for (int et = 0; et < 4; ++et) {
      short4v o;
#pragma unroll
      for (int j = 0; j < 4; ++j)
        o[j] = (short)f2bf(Cs[w * 16 + quad * 4 + j][et * 16 + l16]);
      *(short4v*)(wsb + VB_OFF + vb_idx(bh, QT, w, et, lane)) = o;
    }
  }
}

// ---------------- stats: one block per (bh,KT); Sinv[k] = 1/sum_q exp(K·Q^T) ----------------
// grid (x=bh, y=KT): linear%8 == bh%8 -> all blocks of a bh land on one XCD,
// so the 32x QA re-read hits that XCD's L2 instead of L3/HBM.
__global__ __launch_bounds__(256) void stats_kernel(u16* __restrict__ wsb) {
  int t = threadIdx.x;
  int lane = t & 63, w = t >> 6, quad = lane >> 4, l16 = lane & 15;
  int bh = blockIdx.x;
  int KT = blockIdx.y;

  short8 ka[4][2];
#pragma unroll
  for (int mt = 0; mt < 4; ++mt)
#pragma unroll
    for (int c = 0; c < 2; ++c)
      ka[mt][c] = *(const short8*)(wsb + KA_OFF + frag_idx(bh, KT, mt, c, lane));

  float rs[4][4];
#pragma unroll
  for (int mt = 0; mt < 4; ++mt)
#pragma unroll
    for (int r = 0; r < 4; ++r) rs[mt][r] = 0.f;

  for (int qt = 0; qt < 32; ++qt) {
    short8 qb0 = *(const short8*)(wsb + QA_OFF + frag_idx(bh, qt, w, 0, lane));
    short8 qb1 = *(const short8*)(wsb + QA_OFF + frag_idx(bh, qt, w, 1, lane));
#pragma unroll
    for (int mt = 0; mt < 4; ++mt) {
      f32x4 y = (f32x4){0.f, 0.f, 0.f, 0.f};
      y = __builtin_amdgcn_mfma_f32_16x16x32_bf16(ka[mt][0], qb0, y, 0, 0, 0);
      y = __builtin_amdgcn_mfma_f32_16x16x32_bf16(ka[mt][1], qb1, y, 0, 0, 0);
#pragma unroll
      for (int r = 0; r < 4; ++r) rs[mt][r] += __expf(y[r]);
    }
  }
#pragma unroll
  for (int mt = 0; mt < 4; ++mt)
#pragma unroll
    for (int r = 0; r < 4; ++r) {
      rs[mt][r] += __shfl_xor(rs[mt][r], 1);
      rs[mt][r] += __shfl_xor(rs[mt][r], 2);
      rs[mt][r] += __shfl_xor(rs[mt][r], 4);
      rs[mt][r] += __shfl_xor(rs[mt][r], 8);
    }

  __shared__ float Sred[4][64];
  if (l16 == 0) {
#pragma unroll
    for (int mt = 0; mt < 4; ++mt)
#pragma unroll
      for (int r = 0; r < 4; ++r)
        Sred[w][mt * 16 + quad * 4 + r] = rs[mt][r];
  }
  __syncthreads();
  if (t < 64) {
    float s = Sred[0][t] + Sred[1][t] + Sred[2][t] + Sred[3][t];
    float* S = (float*)(wsb + S_OFF);
    S[(size_t)bh * LL + KT * 64 + t] = 1.0f / s;
  }
}

// ---------------- attn: P = exp(y)*Sinv[k] in registers; direct out ----------------
// grid (x=bh, y=QT) for the same XCD-L2 locality on KA/VB re-reads.
__global__ __launch_bounds__(256, 2) void attn_kernel(const u16* __restrict__ wsb,
                                                      float* __restrict__ out) {
  int t = threadIdx.x;
  int lane = t & 63, w = t >> 6, quad = lane >> 4, l16 = lane & 15;
  int bh = blockIdx.x, b = bh >> 3, h = bh & 7;
  int QT = blockIdx.y, qbase = QT * 64;
  const float* S = (const float*)(wsb + S_OFF) + (size_t)bh * LL;

  short8 qf[4][2];
#pragma unroll
  for (int nt = 0; nt < 4; ++nt)
#pragma unroll
    for (int c = 0; c < 2; ++c)
      qf[nt][c] = *(const short8*)(wsb + QA_OFF + frag_idx(bh, QT, nt, c, lane));

  f32x4 oacc[4][4];
#pragma unroll
  for (int nt = 0; nt < 4; ++nt)
#pragma unroll
    for (int et = 0; et < 4; ++et) oacc[nt][et] = (f32x4){0.f, 0.f, 0.f, 0.f};

  for (int kt = 0; kt < 32; ++kt) {
    short8 ka0 = *(const short8*)(wsb + KA_OFF + frag_idx(bh, kt, w, 0, lane));
    short8 ka1 = *(const short8*)(wsb + KA_OFF + frag_idx(bh, kt, w, 1, lane));
    short4v vb[4];
#pragma unroll
    for (int et = 0; et < 4; ++et)
      vb[et] = *(const short4v*)(wsb + VB_OFF + vb_idx(bh, kt, w, et, lane));
    float4 s4 = *(const float4*)(S + kt * 64 + w * 16 + quad * 4);  // Sinv, broadcast per quad

#pragma unroll
    for (int nt = 0; nt < 4; ++nt) {
      f32x4 y = (f32x4){0.f, 0.f, 0.f, 0.f};
      y = __builtin_amdgcn_mfma_f32_16x16x32_bf16(ka0, qf[nt][0], y, 0, 0, 0);
      y = __builtin_amdgcn_mfma_f32_16x16x32_bf16(ka1, qf[nt][1], y, 0, 0, 0);
      short4v pa;
      pa[0] = (short)f2bf(__expf(y[0]) * s4.x);
      pa[1] = (short)f2bf(__expf(y[1]) * s4.y);
      pa[2] = (short)f2bf(__expf(y[2]) * s4.z);
      pa[3] = (short)f2bf(__expf(y[3]) * s4.w);
#pragma unroll
      for (int et = 0; et < 4; ++et)
        oacc[nt][et] = __builtin_amdgcn_mfma_f32_16x16x16bf16_1k(pa, vb[et], oacc[nt][et], 0, 0, 0);
    }
  }

  __shared__ float red[4][64][68];
#pragma unroll
  for (int nt = 0; nt < 4; ++nt)
#pragma unroll
    for (int et = 0; et < 4; ++et)
#pragma unroll
      for (int r = 0; r < 4; ++r)
        red[w][nt * 16 + quad * 4 + r][et * 16 + l16] = oacc[nt][et][r];
  __syncthreads();
  float* og = out + ((size_t)b * LL + qbase + w * 16) * 512 + h * 64;
#pragma unroll
  for (int i = 0; i < 16; ++i) {
    float s = red[0][w * 16 + i][lane] + red[1][w * 16 + i][lane] +
              red[2][w * 16 + i][lane] + red[3][w * 16 + i][lane];
    og[(size_t)i * 512 + lane] = s;
  }
}

extern "C" void kernel_launch(void* const* d_in, const int* in_sizes, int n_in,
                              void* d_out, int out_size, void* d_ws, size_t ws_size,
                              hipStream_t stream) {
  const float* keys    = (const float*)d_in[0];
  const float* queries = (const float*)d_in[1];
  const float* values  = (const float*)d_in[2];
  const float* WQ      = (const float*)d_in[3];
  const float* WK      = (const float*)d_in[4];
  const float* WV      = (const float*)d_in[5];
  float* out = (float*)d_out;
  u16* wsb = (u16*)d_ws;

  prep_kernel<<<dim3(1152), 256, 0, stream>>>(queries, keys, values, WQ, WK, WV, wsb);
  proj_kernel<<<dim3(32, 16, 3), 256, 0, stream>>>(wsb);
  stats_kernel<<<dim3(16, 32), 256, 0, stream>>>(wsb);
  attn_kernel<<<dim3(16, 32), 256, 0, stream>>>(wsb, out);
}